// Round 9
// baseline (92.526 us; speedup 1.0000x reference)
//
#include <hip/hip_runtime.h>
#include <math.h>

#define NU 100000
#define NI 50000
#define DK 256      // DU == DI
#define EN 128      // E
#define BB 8192
#define TT 24

typedef short short8 __attribute__((ext_vector_type(8)));
typedef float f32x4  __attribute__((ext_vector_type(4)));

// ---- d_ws layout (bytes) ----
#define WPACK_SHORTS 114688
#define WP_OFF     0
#define OWNER_OFF  229376                 // 100000 ints
#define NTAB_OFF   629376                 // 50000*128 bf16 = 12.8 MB
#define NPART_OFF  13429376               // 8192*128 f32  = 4 MB
#define ATAB_OFF   17623680               // 50000*128 bf16 = 12.8 MB

// wpack element offsets (bf16 shorts, all [N][K] k-contiguous)
#define OFF_IWT   0        // 128x256
#define OFF_UWT   32768    // 128x256
#define OFF_AW1UT 65536    // 128x128 (aW1 rows 0..127   -> neigh part)
#define OFF_AW1LT 81920    // 128x128 (aW1 rows 128..255 -> node part)
#define OFF_AW2T  98304    // 128x128

#define NBLK_NEIGH 782     // ceil(NI/64)
#define NBLK_NF    128     // BB/64
#define NBLK_PACK  448     // WPACK_SHORTS/256
#define GGA 4              // batch rows per attn block
#define ATTN_BLKS  (BB / GGA)

__device__ __forceinline__ unsigned short f2b(float x) {
    unsigned int u = __float_as_uint(x);
    u = (u + 0x7FFFu + ((u >> 16) & 1u)) >> 16;   // RNE, finite inputs
    return (unsigned short)u;
}
__device__ __forceinline__ float b2f(unsigned short v) {
    return __uint_as_float(((unsigned int)v) << 16);
}
__device__ __forceinline__ unsigned int cvtpk_bf16(float lo, float hi) {
    unsigned int r;
    asm("v_cvt_pk_bf16_f32 %0, %1, %2" : "=v"(r) : "v"(lo), "v"(hi));
    return r;
}
__device__ __forceinline__ short8 pack8(float v0, float v1, float v2, float v3,
                                        float v4, float v5, float v6, float v7) {
    union { short8 s; unsigned int u[4]; } x;
    x.u[0] = cvtpk_bf16(v0, v1);
    x.u[1] = cvtpk_bf16(v2, v3);
    x.u[2] = cvtpk_bf16(v4, v5);
    x.u[3] = cvtpk_bf16(v6, v7);
    return x.s;
}

#define MFMA(a, b, c) __builtin_amdgcn_mfma_f32_16x16x32_bf16((a), (b), (c), 0, 0, 0)
#define LDROW(buf, stride, row, k) \
    (*reinterpret_cast<const short8*>(reinterpret_cast<const char*>(buf) + (row) * (stride) + (k) * 2))

// ---- K1 (tiny): pack weights + owner reset ----
__global__ __launch_bounds__(256)
void prep_kernel(const int* __restrict__ nodes,
                 const float* __restrict__ uW, const float* __restrict__ iW,
                 const float* __restrict__ aW1, const float* __restrict__ aW2,
                 short* __restrict__ wp, int* __restrict__ owner)
{
    if (blockIdx.x < NBLK_PACK) {
        int i = blockIdx.x * 256 + threadIdx.x;
        float v;
        if (i < 32768)      { int j = i;         int n = j >> 8, k = j & 255; v = iW[k * EN + n]; }
        else if (i < 65536) { int j = i - 32768; int n = j >> 8, k = j & 255; v = uW[k * EN + n]; }
        else if (i < 81920) { int j = i - 65536; int n = j >> 7, k = j & 127; v = aW1[k * EN + n]; }
        else if (i < 98304) { int j = i - 81920; int n = j >> 7, k = j & 127; v = aW1[(128 + k) * EN + n]; }
        else                { int j = i - 98304; int n = j >> 7, k = j & 127; v = aW2[k * EN + n]; }
        wp[i] = (short)f2b(v);
    } else {
        int b = (blockIdx.x - NBLK_PACK) * 256 + threadIdx.x;
        if (b < BB) owner[nodes[b]] = -1;
    }
}

// ---- K2: neighs+atab table | nf/npart (+owner max) ; tail-zero of out_embed ----
__global__ __launch_bounds__(256, 4)
void embed_kernel(const int* __restrict__ nodes,
                  const float* __restrict__ u_weight, const float* __restrict__ i_weight,
                  const float* __restrict__ ub, const float* __restrict__ ib,
                  const float* __restrict__ ab1,
                  const short* __restrict__ wp, int* __restrict__ owner,
                  short* __restrict__ ntab, short* __restrict__ atab,
                  float* __restrict__ out_nf, float* __restrict__ npart,
                  float* __restrict__ out_embed)
{
    __shared__ __align__(16) char smem[33792];   // staging (528B x 64); overlaid: sO @264 (lower), A-out @264 (upper)
    __shared__ int sNd[64];

    const int tid = threadIdx.x;
    const int l = tid & 63, lr = l & 15, lq = l >> 4, n0 = (tid >> 6) * 32;
    const int kA = lq * 8, nc0 = n0 + lr, nc1 = n0 + 16 + lr;

    if (blockIdx.x < NBLK_NEIGH) {
        // ======== neighs path: ntab[r] = bf16(i_weight[r] @ iW + ib); atab = ntab @ aW1U ========
        const int r0 = blockIdx.x * 64;
        const int nrows = (NI - r0 < 64) ? (NI - r0) : 64;

        for (int task = tid; task < 64 * 32; task += 256) {
            int row = task >> 5, c = task & 31;
            if (row < nrows) {
                const float* src = i_weight + (size_t)(r0 + row) * DK + c * 8;
                float4 f0 = *(const float4*)src;
                float4 f1 = *(const float4*)(src + 4);
                short8 o;
                o[0]=f2b(f0.x); o[1]=f2b(f0.y); o[2]=f2b(f0.z); o[3]=f2b(f0.w);
                o[4]=f2b(f1.x); o[5]=f2b(f1.y); o[6]=f2b(f1.z); o[7]=f2b(f1.w);
                *reinterpret_cast<short8*>(smem + row * 528 + c * 16) = o;
            }
        }
        __syncthreads();

        const short* iWt = wp + OFF_IWT;
        f32x4 acc[4][2];
        #pragma unroll
        for (int m = 0; m < 4; ++m) { acc[m][0] = {0.f,0.f,0.f,0.f}; acc[m][1] = {0.f,0.f,0.f,0.f}; }
        #pragma unroll
        for (int ks = 0; ks < 8; ++ks) {
            int k = ks * 32 + kA;
            short8 w0 = *reinterpret_cast<const short8*>(iWt + nc0 * DK + k);
            short8 w1 = *reinterpret_cast<const short8*>(iWt + nc1 * DK + k);
            #pragma unroll
            for (int m = 0; m < 4; ++m) {
                short8 a = LDROW(smem, 528, m * 16 + lr, k);
                acc[m][0] = MFMA(a, w0, acc[m][0]);
                acc[m][1] = MFMA(a, w1, acc[m][1]);
            }
        }
        __syncthreads();   // A-staging reads done; overlay bf16 output tile sO @264
        {
            float ib0 = ib[nc0], ib1 = ib[nc1];
            #pragma unroll
            for (int m = 0; m < 4; ++m)
                #pragma unroll
                for (int nt = 0; nt < 2; ++nt) {
                    int n = nt ? nc1 : nc0;
                    float bv = nt ? ib1 : ib0;
                    #pragma unroll
                    for (int r = 0; r < 4; ++r) {
                        int row = m * 16 + lq * 4 + r;
                        *reinterpret_cast<short*>(smem + row * 264 + n * 2)
                            = (short)f2b(acc[m][nt][r] + bv);
                    }
                }
        }
        __syncthreads();

        // copy sO -> ntab, and GEMM2: atab-tile = sO @ aW1Ut (K=128)
        for (int g = tid; g < nrows * 16; g += 256) {
            int row = g >> 4, s = g & 15;
            short8 v = *reinterpret_cast<const short8*>(smem + row * 264 + s * 16);
            *reinterpret_cast<short8*>(ntab + (size_t)(r0 + row) * EN + s * 8) = v;
        }
        const short* aW1Ut = wp + OFF_AW1UT;
        f32x4 ac2[4][2];
        #pragma unroll
        for (int m = 0; m < 4; ++m) { ac2[m][0] = {0.f,0.f,0.f,0.f}; ac2[m][1] = {0.f,0.f,0.f,0.f}; }
        #pragma unroll
        for (int ks = 0; ks < 4; ++ks) {
            int k = ks * 32 + kA;
            short8 w0 = *reinterpret_cast<const short8*>(aW1Ut + nc0 * EN + k);
            short8 w1 = *reinterpret_cast<const short8*>(aW1Ut + nc1 * EN + k);
            #pragma unroll
            for (int m = 0; m < 4; ++m) {
                short8 a = LDROW(smem, 264, m * 16 + lr, k);
                ac2[m][0] = MFMA(a, w0, ac2[m][0]);
                ac2[m][1] = MFMA(a, w1, ac2[m][1]);
            }
        }
        // epilogue into upper overlay (disjoint from sO region; per-wave writes)
        {
            char* up = smem + 16896;
            #pragma unroll
            for (int m = 0; m < 4; ++m)
                #pragma unroll
                for (int nt = 0; nt < 2; ++nt) {
                    int n = nt ? nc1 : nc0;
                    #pragma unroll
                    for (int r = 0; r < 4; ++r) {
                        int row = m * 16 + lq * 4 + r;
                        *reinterpret_cast<short*>(up + row * 264 + n * 2)
                            = (short)f2b(ac2[m][nt][r]);
                    }
                }
        }
        __syncthreads();
        for (int g = tid; g < nrows * 16; g += 256) {
            int row = g >> 4, s = g & 15;
            short8 v = *reinterpret_cast<const short8*>(smem + 16896 + row * 264 + s * 16);
            *reinterpret_cast<short8*>(atab + (size_t)(r0 + row) * EN + s * 8) = v;
        }
    } else {
        // ======== nf path: out_nf + npart for 64 batch rows; also owner atomicMax ========
        const int bblk = blockIdx.x - NBLK_NEIGH;
        const int r0 = bblk * 64;
        {
            int bq = bblk * 256 + tid;
            if (bq < BB) atomicMax(&owner[nodes[bq]], bq);
        }
        if (tid < 64) sNd[tid] = nodes[r0 + tid];
        __syncthreads();

        for (int task = tid; task < 64 * 32; task += 256) {
            int row = task >> 5, c = task & 31;
            const float* src = u_weight + (size_t)sNd[row] * DK + c * 8;
            float4 f0 = *(const float4*)src;
            float4 f1 = *(const float4*)(src + 4);
            short8 o;
            o[0]=f2b(f0.x); o[1]=f2b(f0.y); o[2]=f2b(f0.z); o[3]=f2b(f0.w);
            o[4]=f2b(f1.x); o[5]=f2b(f1.y); o[6]=f2b(f1.z); o[7]=f2b(f1.w);
            *reinterpret_cast<short8*>(smem + row * 528 + c * 16) = o;
        }
        __syncthreads();

        const short* uWt   = wp + OFF_UWT;
        const short* aW1Lt = wp + OFF_AW1LT;

        f32x4 acc[4][2];
        #pragma unroll
        for (int m = 0; m < 4; ++m) { acc[m][0] = {0.f,0.f,0.f,0.f}; acc[m][1] = {0.f,0.f,0.f,0.f}; }
        #pragma unroll
        for (int ks = 0; ks < 8; ++ks) {
            int k = ks * 32 + kA;
            short8 w0 = *reinterpret_cast<const short8*>(uWt + nc0 * DK + k);
            short8 w1 = *reinterpret_cast<const short8*>(uWt + nc1 * DK + k);
            #pragma unroll
            for (int m = 0; m < 4; ++m) {
                short8 a = LDROW(smem, 528, m * 16 + lr, k);
                acc[m][0] = MFMA(a, w0, acc[m][0]);
                acc[m][1] = MFMA(a, w1, acc[m][1]);
            }
        }
        __syncthreads();   // A reads done; overlay bf16 nf tile (272B stride)
        {
            float b0v = ub[nc0], b1v = ub[nc1];
            #pragma unroll
            for (int m = 0; m < 4; ++m)
                #pragma unroll
                for (int nt = 0; nt < 2; ++nt) {
                    int n = nt ? nc1 : nc0;
                    float bv = nt ? b1v : b0v;
                    #pragma unroll
                    for (int r = 0; r < 4; ++r) {
                        int row = m * 16 + lq * 4 + r;
                        float v = acc[m][nt][r] + bv;
                        out_nf[(size_t)(r0 + row) * EN + n] = v;
                        *reinterpret_cast<short*>(smem + row * 272 + n * 2) = (short)f2b(v);
                    }
                }
        }
        __syncthreads();

        f32x4 ap[4][2];
        #pragma unroll
        for (int m = 0; m < 4; ++m) { ap[m][0] = {0.f,0.f,0.f,0.f}; ap[m][1] = {0.f,0.f,0.f,0.f}; }
        #pragma unroll
        for (int ks = 0; ks < 4; ++ks) {
            int k = ks * 32 + kA;
            short8 w0 = *reinterpret_cast<const short8*>(aW1Lt + nc0 * EN + k);
            short8 w1 = *reinterpret_cast<const short8*>(aW1Lt + nc1 * EN + k);
            #pragma unroll
            for (int m = 0; m < 4; ++m) {
                short8 a = LDROW(smem, 272, m * 16 + lr, k);
                ap[m][0] = MFMA(a, w0, ap[m][0]);
                ap[m][1] = MFMA(a, w1, ap[m][1]);
            }
        }
        {
            float b0v = ab1[nc0], b1v = ab1[nc1];
            #pragma unroll
            for (int m = 0; m < 4; ++m)
                #pragma unroll
                for (int nt = 0; nt < 2; ++nt) {
                    int n = nt ? nc1 : nc0;
                    float bv = nt ? b1v : b0v;
                    #pragma unroll
                    for (int r = 0; r < 4; ++r) {
                        int row = m * 16 + lq * 4 + r;
                        npart[(size_t)(r0 + row) * EN + n] = ap[m][nt][r] + bv;
                    }
                }
        }
    }

    // ---- tail zero of out_embed (unconditional; attn overwrites batch rows later) ----
    {
        float4* embed4 = (float4*)out_embed;
        const int n16 = NU * EN / 4;
        const int gsz = (NBLK_NEIGH + NBLK_NF) * 256;
        float4 z = {0.f, 0.f, 0.f, 0.f};
        for (int i = blockIdx.x * 256 + tid; i < n16; i += gsz) embed4[i] = z;
    }
}

// ---- K3: attn, barrier-free; wave w owns batch row b0+w end-to-end ----
__global__ __launch_bounds__(256)
void attn_kernel(const int* __restrict__ nodes, const int* __restrict__ neigh_idx,
                 const float* __restrict__ ab2, const float* __restrict__ aW3,
                 const short* __restrict__ wp, const short* __restrict__ ntab,
                 const short* __restrict__ atab, const float* __restrict__ npart,
                 const int* __restrict__ owner, float* __restrict__ out_embed)
{
    __shared__ __align__(16) short sNg[GGA][24 * 136];  // 272B row stride, wave-local
    __shared__ float sLg[GGA][32];

    const int tid = threadIdx.x;
    const int w = tid >> 6, l = tid & 63;
    const int lr = l & 15, lq = l >> 4;
    const int b = blockIdx.x * GGA + w;
    const int ibase = b * TT;

    // gather 24 neighbor rows (wave-local; no barrier needed anywhere in this kernel)
    #pragma unroll
    for (int j = 0; j < 6; ++j) {
        int task = j * 64 + l;                 // 0..383 = 24 rows x 16 segs
        int trow = task >> 4, s = task & 15;
        int idx = neigh_idx[ibase + trow];
        short8 v = *reinterpret_cast<const short8*>(ntab + (size_t)idx * EN + s * 8);
        *reinterpret_cast<short8*>(reinterpret_cast<char*>(&sNg[w][0]) + trow * 272 + s * 16) = v;
    }

    // ---- build h2 A-fragments in registers: h1 = relu(atab[idx] + npart[b]) ----
    const int rowA1 = (16 + lr < TT) ? (16 + lr) : 0;     // pad rows -> row 0 (logits masked later)
    const int idxA0 = neigh_idx[ibase + lr];
    const int idxA1 = neigh_idx[ibase + rowA1];

    short8 afr0[4], afr1[4];
    #pragma unroll
    for (int ks = 0; ks < 4; ++ks) {
        int e0 = ks * 32 + lq * 8;
        float4 np0 = *reinterpret_cast<const float4*>(npart + (size_t)b * EN + e0);
        float4 np1 = *reinterpret_cast<const float4*>(npart + (size_t)b * EN + e0 + 4);
        short8 a0 = *reinterpret_cast<const short8*>(atab + (size_t)idxA0 * EN + e0);
        short8 a1 = *reinterpret_cast<const short8*>(atab + (size_t)idxA1 * EN + e0);
        afr0[ks] = pack8(
            fmaxf(b2f((unsigned short)a0[0]) + np0.x, 0.f), fmaxf(b2f((unsigned short)a0[1]) + np0.y, 0.f),
            fmaxf(b2f((unsigned short)a0[2]) + np0.z, 0.f), fmaxf(b2f((unsigned short)a0[3]) + np0.w, 0.f),
            fmaxf(b2f((unsigned short)a0[4]) + np1.x, 0.f), fmaxf(b2f((unsigned short)a0[5]) + np1.y, 0.f),
            fmaxf(b2f((unsigned short)a0[6]) + np1.z, 0.f), fmaxf(b2f((unsigned short)a0[7]) + np1.w, 0.f));
        afr1[ks] = pack8(
            fmaxf(b2f((unsigned short)a1[0]) + np0.x, 0.f), fmaxf(b2f((unsigned short)a1[1]) + np0.y, 0.f),
            fmaxf(b2f((unsigned short)a1[2]) + np0.z, 0.f), fmaxf(b2f((unsigned short)a1[3]) + np0.w, 0.f),
            fmaxf(b2f((unsigned short)a1[4]) + np1.x, 0.f), fmaxf(b2f((unsigned short)a1[5]) + np1.y, 0.f),
            fmaxf(b2f((unsigned short)a1[6]) + np1.z, 0.f), fmaxf(b2f((unsigned short)a1[7]) + np1.w, 0.f));
    }

    // ---- h2 GEMM: rows 0..31 (24 real) x all 128 cols, K=128 ----
    const short* aW2t = wp + OFF_AW2T;
    f32x4 acc0[8], acc1[8];
    #pragma unroll
    for (int nt = 0; nt < 8; ++nt) { acc0[nt] = {0.f,0.f,0.f,0.f}; acc1[nt] = {0.f,0.f,0.f,0.f}; }
    #pragma unroll
    for (int nt = 0; nt < 8; ++nt) {
        int nrow = nt * 16 + lr;
        #pragma unroll
        for (int ks = 0; ks < 4; ++ks) {
            short8 wv = *reinterpret_cast<const short8*>(aW2t + nrow * EN + ks * 32 + lq * 8);
            acc0[nt] = MFMA(afr0[ks], wv, acc0[nt]);
            acc1[nt] = MFMA(afr1[ks], wv, acc1[nt]);
        }
    }

    // ---- logits: relu(h2 + ab2) . aW3, reduced over cols in-register ----
    float lp0[4] = {0.f,0.f,0.f,0.f}, lp1[4] = {0.f,0.f,0.f,0.f};
    #pragma unroll
    for (int nt = 0; nt < 8; ++nt) {
        int c = nt * 16 + lr;
        float bv = ab2[c], wv = aW3[c];
        #pragma unroll
        for (int r = 0; r < 4; ++r) {
            lp0[r] += fmaxf(acc0[nt][r] + bv, 0.f) * wv;
            lp1[r] += fmaxf(acc1[nt][r] + bv, 0.f) * wv;
        }
    }
    #pragma unroll
    for (int r = 0; r < 4; ++r) {
        float v0 = lp0[r], v1 = lp1[r];
        v0 += __shfl_xor(v0, 1, 16); v0 += __shfl_xor(v0, 2, 16);
        v0 += __shfl_xor(v0, 4, 16); v0 += __shfl_xor(v0, 8, 16);
        v1 += __shfl_xor(v1, 1, 16); v1 += __shfl_xor(v1, 2, 16);
        v1 += __shfl_xor(v1, 4, 16); v1 += __shfl_xor(v1, 8, 16);
        if (lr == 0) {
            sLg[w][lq * 4 + r]      = v0;   // rows 0..15
            sLg[w][16 + lq * 4 + r] = v1;   // rows 16..31 (24..31 pad, masked below)
        }
    }

    // ---- in-wave softmax over T=24 (ab3 constant cancels in softmax) ----
    float lg = (l < TT) ? sLg[w][l] : -1e30f;
    float mx = lg;
    #pragma unroll
    for (int d = 32; d > 0; d >>= 1) mx = fmaxf(mx, __shfl_xor(mx, d, 64));
    float p = (l < TT) ? __expf(lg - mx) : 0.f;
    float s = p;
    #pragma unroll
    for (int d = 32; d > 0; d >>= 1) s += __shfl_xor(s, d, 64);
    float att = p / s;

    // ---- agg + scatter: lane l covers cols l and l+64 ----
    {
        float a0 = 0.f, a1 = 0.f;
        #pragma unroll
        for (int t = 0; t < TT; ++t) {
            float wt = __shfl(att, t, 64);
            const char* rbase = reinterpret_cast<const char*>(&sNg[w][0]) + t * 272;
            a0 += wt * b2f(*reinterpret_cast<const unsigned short*>(rbase + l * 2));
            a1 += wt * b2f(*reinterpret_cast<const unsigned short*>(rbase + (l + 64) * 2));
        }
        int node = nodes[b];
        if (owner[node] == b) {
            out_embed[(size_t)node * EN + l]      = a0;
            out_embed[(size_t)node * EN + 64 + l] = a1;
        }
    }
}

extern "C" void kernel_launch(void* const* d_in, const int* in_sizes, int n_in,
                              void* d_out, int out_size, void* d_ws, size_t ws_size,
                              hipStream_t stream) {
    const int*   nodes     = (const int*)d_in[0];
    const int*   neigh_idx = (const int*)d_in[1];
    const float* u_weight  = (const float*)d_in[2];
    const float* i_weight  = (const float*)d_in[3];
    const float* uW  = (const float*)d_in[4];
    const float* ub  = (const float*)d_in[5];
    const float* iW  = (const float*)d_in[6];
    const float* ib  = (const float*)d_in[7];
    const float* aW1 = (const float*)d_in[8];
    const float* ab1 = (const float*)d_in[9];
    const float* aW2 = (const float*)d_in[10];
    const float* ab2 = (const float*)d_in[11];
    const float* aW3 = (const float*)d_in[12];

    float* out_nf    = (float*)d_out;
    float* out_embed = out_nf + (size_t)BB * EN;

    char*  ws    = (char*)d_ws;
    short* wpack = (short*)(ws + WP_OFF);
    int*   owner = (int*)(ws + OWNER_OFF);
    short* ntab  = (short*)(ws + NTAB_OFF);
    float* npart = (float*)(ws + NPART_OFF);
    short* atab  = (short*)(ws + ATAB_OFF);

    prep_kernel<<<NBLK_PACK + 32, 256, 0, stream>>>(nodes, uW, iW, aW1, aW2, wpack, owner);
    embed_kernel<<<NBLK_NEIGH + NBLK_NF, 256, 0, stream>>>(
        nodes, u_weight, i_weight, ub, ib, ab1, wpack, owner, ntab, atab, out_nf, npart, out_embed);
    attn_kernel<<<ATTN_BLKS, 256, 0, stream>>>(nodes, neigh_idx, ab2, aW3,
                                               wpack, ntab, atab, npart, owner, out_embed);
}